// Round 5
// baseline (111.004 us; speedup 1.0000x reference)
//
#include <hip/hip_runtime.h>
#include <hip/hip_bf16.h>
#include <stdint.h>

// Problem: B=32, N=512, C=16, D=O=256.  Flattened nodes = 16384.
#define CC 16
#define OO 256
#define NSLAB 24            // K = 768 = 24 slabs of 32
#define SLAB_ELS 2048       // 64 rows x 32 k per (mtile,slab) chunk
#define MT_ELS (NSLAB * SLAB_ELS)        // 49152 bf16 per mtile
#define AGG_ELS (16384 * 768)            // 25.2 MB
#define NB_ELS  (16384 * 256)            // bf16 nodes, 8 MB

typedef __attribute__((ext_vector_type(8))) short bf16x8;
typedef __attribute__((ext_vector_type(4))) float f32x4;

__device__ __forceinline__ unsigned short f2bf(float x) {
    unsigned u = __builtin_bit_cast(unsigned, x);
    u += 0x7FFFu + ((u >> 16) & 1u);
    return (unsigned short)(u >> 16);
}

__device__ __forceinline__ void st_bf4(unsigned short* p, float4 v) {
    uint2 u;
    u.x = (unsigned)f2bf(v.x) | ((unsigned)f2bf(v.y) << 16);
    u.y = (unsigned)f2bf(v.z) | ((unsigned)f2bf(v.w) << 16);
    *(uint2*)p = u;
}

// async 16B global -> LDS (wave-uniform LDS base + lane*16)
__device__ __forceinline__ void cp16(const void* g, void* l) {
    __builtin_amdgcn_global_load_lds(
        (const __attribute__((address_space(1))) unsigned int*)g,
        (__attribute__((address_space(3))) unsigned int*)l, 16, 0, 0);
}

// ---------------------------------------------------------------------------
// Kernel 0: prep — nodes fp32 -> bf16 (nb), weights fp32 -> bf16 K-slab-major
// ---------------------------------------------------------------------------
__global__ __launch_bounds__(256) void prep(
    const float* __restrict__ nodes, const float* __restrict__ wt,
    const float* __restrict__ wrp, const float* __restrict__ wl,
    unsigned short* __restrict__ nb, unsigned short* __restrict__ wsb) {

    __shared__ unsigned short T[256 * 40];
    const int p = blockIdx.x;
    const int tid = threadIdx.x;

    if (p < 2048) {                      // nodes -> bf16, 8 elems/thread
        const size_t t = (size_t)p * 256 + tid;
        const float4* s = (const float4*)nodes + t * 2;
        float4 a = s[0], b = s[1];
        uint4 u;
        u.x = (unsigned)f2bf(a.x) | ((unsigned)f2bf(a.y) << 16);
        u.y = (unsigned)f2bf(a.z) | ((unsigned)f2bf(a.w) << 16);
        u.z = (unsigned)f2bf(b.x) | ((unsigned)f2bf(b.y) << 16);
        u.w = (unsigned)f2bf(b.z) | ((unsigned)f2bf(b.w) << 16);
        *(uint4*)(nb + t * 8) = u;
        return;
    }
    // ---- weight prep: one block per K-slab, LDS transpose ----
    const int slab = p - 2048;           // 0..23
    const int n = tid;                   // 0..255
#pragma unroll
    for (int kk = 0; kk < 32; ++kk) {
        const int k = slab * 32 + kk;    // 0..255 w_t, 256..511 w_r, 512..767 w_l
        const float* s = (k < 256) ? wt : ((k < 512) ? wrp : wl);
        T[n * 40 + kk] = f2bf(s[(k & 255) * OO + n]);
    }
    __syncthreads();
    uint4* dst = (uint4*)(wsb + slab * 8192 + n * 32);
    const uint4* src = (const uint4*)&T[n * 40];
#pragma unroll
    for (int q = 0; q < 4; ++q) dst[q] = src[q];
}

// ---------------------------------------------------------------------------
// Kernel 1: gather + coefficient reduce -> agg[mtile][slab][row64][kw32]
// One node per wave: children row bases are wave-uniform scalars; 16 bf16
// row gathers (8 B/lane) in flight; parent read fp32 for precision.
// XCD swizzle: XCD x owns nodes [x*2048, (x+1)*2048)  (4 whole batches).
// ---------------------------------------------------------------------------
__global__ __launch_bounds__(256, 8) void gather(
    const float* __restrict__ nodes, const unsigned short* __restrict__ nb,
    const int* __restrict__ children, unsigned short* __restrict__ agg) {

    const int wave = threadIdx.x >> 6;
    const int lane = threadIdx.x & 63;
    const int p = blockIdx.x;                    // 4096 blocks
    const int g = (p & 7) * 512 + (p >> 3);      // node-group, XCD-local
    const int nf = __builtin_amdgcn_readfirstlane(g * 4 + wave);
    const int brow = nf & ~511;                  // b*512

    const int* chp = children + (nf << 4);
    int cj[CC];
#pragma unroll
    for (int j = 0; j < CC; ++j) cj[j] = chp[j];     // scalar loads
    int ns = 0;
#pragma unroll
    for (int j = 0; j < CC; ++j) ns += (cj[j] != 0) ? 1 : 0;
    const float inv_den = (ns > 1) ? 1.0f / (float)(ns - 1) : 0.0f;
    const bool single = (ns == 1);

    // ---- issue all loads: parent fp32 (16 B/lane) + 16 children bf16 (8 B) --
    const float4* g4 = (const float4*)nodes;
    float4 pt = g4[(size_t)nf * 64 + lane];          // lane owns dims lane*4..+4
    uint2 ec[CC];
#pragma unroll
    for (int j = 0; j < CC; ++j)
        ec[j] = *(const uint2*)(nb + ((size_t)(brow + cj[j]) << 8) + (lane << 2));

    // ---- reduce (reference _coefs, branchless) ----
    float4 ar = make_float4(0.f, 0.f, 0.f, 0.f);
    float4 al = make_float4(0.f, 0.f, 0.f, 0.f);
#pragma unroll
    for (int j = 0; j < CC; ++j) {
        const float hasf = (cj[j] != 0) ? 1.0f : 0.0f;
        const float crr = single ? ((j == 0) ? 0.5f : 0.0f) : (float)j * inv_den;
        const float cr = crr * hasf;
        const float cl = (1.0f - crr) * hasf;
        const float e0 = __builtin_bit_cast(float, ec[j].x << 16);
        const float e1 = __builtin_bit_cast(float, ec[j].x & 0xFFFF0000u);
        const float e2 = __builtin_bit_cast(float, ec[j].y << 16);
        const float e3 = __builtin_bit_cast(float, ec[j].y & 0xFFFF0000u);
        ar.x += cr * e0; ar.y += cr * e1; ar.z += cr * e2; ar.w += cr * e3;
        al.x += cl * e0; al.y += cl * e1; al.z += cl * e2; al.w += cl * e3;
    }

    // ---- store agg (same layout as GEMM staging expects) ----
    const int sl  = lane >> 3;                   // slab within 256-k part
    const int kwb = (lane & 7) * 4;
    unsigned short* rowp = agg + (size_t)(nf >> 6) * MT_ELS
                               + (size_t)(nf & 63) * 32 + kwb;
    st_bf4(rowp + (size_t)(0  + sl) * SLAB_ELS, pt);   // k 0..255   : w_t
    st_bf4(rowp + (size_t)(8  + sl) * SLAB_ELS, ar);   // k 256..511 : w_r
    st_bf4(rowp + (size_t)(16 + sl) * SLAB_ELS, al);   // k 512..767 : w_l
}

// ---------------------------------------------------------------------------
// Kernel 2: GEMM (16384 x 768) x (768 x 256) + bias + leaky_relu -> out fp32
// 64x128 tile, 512 blocks (2/CU), dbuf LDS, global_load_lds staging.
// Block swizzle matches gather's XCD ownership -> agg slabs hit LOCAL L2.
// ---------------------------------------------------------------------------
__global__ __launch_bounds__(256, 2) void gemm_ep(
    const unsigned short* __restrict__ agg, const unsigned short* __restrict__ wsb,
    const float* __restrict__ conv, float* __restrict__ out) {

    __shared__ unsigned short Ab[2][SLAB_ELS];   // 2 x 4 KB
    __shared__ unsigned short Bb[2][4096];       // 2 x 8 KB

    const int tid  = threadIdx.x;
    const int wave = tid >> 6;
    const int lane = tid & 63;
    const int quad = lane >> 4;
    const int l16  = lane & 15;
    // XCD-aligned mapping: mtile m covers nodes m*64, gathered on XCD (m>>5).
    const int x = blockIdx.x & 7;
    const int q = blockIdx.x >> 3;               // 0..63
    const int mtile = x * 32 + (q >> 1);         // 0..255
    const int ntile = q & 1;
    const int wrr = wave >> 1;                   // M half (32 rows)
    const int wcc = wave & 1;                    // N half (64 cols)

    const char* aggb = (const char*)agg + (size_t)mtile * (MT_ELS * 2);
    const char* wsbb = (const char*)wsb + ntile * 8192;
    const int toff  = tid * 16;
    const int wbase = (tid & ~63) * 16;          // wave-uniform LDS offset

    f32x4 acc[2][4];
#pragma unroll
    for (int mi = 0; mi < 2; ++mi)
#pragma unroll
        for (int ni = 0; ni < 4; ++ni)
            acc[mi][ni] = (f32x4){0.f, 0.f, 0.f, 0.f};

    auto stage = [&](int s, int b) {
        const char* ga = aggb + s * 4096 + toff;           // 4 KB A chunk
        cp16(ga, (char*)&Ab[b][0] + wbase);
        const char* gb = wsbb + s * 16384 + toff;          // 8 KB B chunk
        cp16(gb,        (char*)&Bb[b][0] + wbase);
        cp16(gb + 4096, (char*)&Bb[b][0] + wbase + 4096);
    };

    stage(0, 0);
#pragma unroll 1
    for (int s = 0; s < NSLAB; ++s) {
        const int cur = s & 1;
        __syncthreads();                  // staging of slab s complete
        if (s + 1 < NSLAB) stage(s + 1, cur ^ 1);

        bf16x8 af[2], bfr[4];
#pragma unroll
        for (int mi = 0; mi < 2; ++mi)
            af[mi] = *(const bf16x8*)&Ab[cur][(wrr * 32 + mi * 16 + l16) * 32 + quad * 8];
#pragma unroll
        for (int ni = 0; ni < 4; ++ni)
            bfr[ni] = *(const bf16x8*)&Bb[cur][(wcc * 64 + ni * 16 + l16) * 32 + quad * 8];
#pragma unroll
        for (int mi = 0; mi < 2; ++mi)
#pragma unroll
            for (int ni = 0; ni < 4; ++ni)
                acc[mi][ni] = __builtin_amdgcn_mfma_f32_16x16x32_bf16(
                    af[mi], bfr[ni], acc[mi][ni], 0, 0, 0);
    }

    // epilogue: + conv, leaky_relu(0.01), fp32 store
#pragma unroll
    for (int ni = 0; ni < 4; ++ni) {
        const int col = ntile * 128 + wcc * 64 + ni * 16 + l16;
        const float cv = conv[col];
#pragma unroll
        for (int mi = 0; mi < 2; ++mi) {
#pragma unroll
            for (int r = 0; r < 4; ++r) {
                const int row = mtile * 64 + wrr * 32 + mi * 16 + quad * 4 + r;
                float v = acc[mi][ni][r] + cv;
                v = (v > 0.f) ? v : 0.01f * v;
                out[(size_t)row * OO + col] = v;
            }
        }
    }
}

extern "C" void kernel_launch(void* const* d_in, const int* in_sizes, int n_in,
                              void* d_out, int out_size, void* d_ws, size_t ws_size,
                              hipStream_t stream) {
    // setup_inputs order: nodes, w_t, w_l, w_r, conv, children
    const float* nodes    = (const float*)d_in[0];
    const float* w_t      = (const float*)d_in[1];
    const float* w_l      = (const float*)d_in[2];
    const float* w_r      = (const float*)d_in[3];
    const float* conv     = (const float*)d_in[4];
    const int*   children = (const int*)d_in[5];

    unsigned short* agg = (unsigned short*)d_ws;          // 25,165,824 B
    unsigned short* wsb = agg + AGG_ELS;                  // +   393,216 B
    unsigned short* nbb = wsb + 768 * 256;                // + 8,388,608 B

    prep<<<2048 + 24, 256, 0, stream>>>(nodes, w_t, w_r, w_l, nbb, wsb);
    gather<<<4096, 256, 0, stream>>>(nodes, nbb, children, agg);
    gemm_ep<<<512, 256, 0, stream>>>(agg, wsb, conv, (float*)d_out);
}

// Round 6
// 110.297 us; speedup vs baseline: 1.0064x; 1.0064x over previous
//
#include <hip/hip_runtime.h>
#include <hip/hip_bf16.h>
#include <stdint.h>

// Problem: B=32, N=512, C=16, D=O=256.  Flattened nodes = 16384.
// agg: row-major bf16 [16384][768]; k 0..255 = bf16 nodes (w_t part, written
// by prep), k 256..511 = ar (w_r part), k 512..767 = al (w_l part).
#define CC 16
#define OO 256
#define NSLAB 24            // K = 768 = 24 slabs of 32
#define AGG_ELS (16384 * 768)            // 25.2 MB

typedef __attribute__((ext_vector_type(8))) short bf16x8;
typedef __attribute__((ext_vector_type(4))) float f32x4;

__device__ __forceinline__ unsigned short f2bf(float x) {
    unsigned u = __builtin_bit_cast(unsigned, x);
    u += 0x7FFFu + ((u >> 16) & 1u);
    return (unsigned short)(u >> 16);
}

// async 16B global -> LDS; global addr is PER-LANE, LDS dest is base+lane*16
__device__ __forceinline__ void cp16(const void* g, void* l) {
    __builtin_amdgcn_global_load_lds(
        (const __attribute__((address_space(1))) unsigned int*)g,
        (__attribute__((address_space(3))) unsigned int*)l, 16, 0, 0);
}

// ---------------------------------------------------------------------------
// Kernel 0: prep — nodes fp32 -> bf16 into agg[:, 0:256]; weights -> wsb.
// Node blocks XCD-swizzled so the XCD that converts rows also owns them.
// ---------------------------------------------------------------------------
__global__ __launch_bounds__(256) void prep(
    const float* __restrict__ nodes, const float* __restrict__ wt,
    const float* __restrict__ wrp, const float* __restrict__ wl,
    unsigned short* __restrict__ agg, unsigned short* __restrict__ wsb) {

    __shared__ unsigned short T[256 * 40];
    const int p = blockIdx.x;
    const int tid = threadIdx.x;

    if (p < 2048) {                       // 8 rows per block, swizzled per XCD
        const int pp = (p & 7) * 256 + (p >> 3);
        const size_t t = (size_t)pp * 256 + tid;   // 8 fp32 per thread
        const float4* s = (const float4*)nodes + t * 2;
        float4 a = s[0], b = s[1];
        uint4 u;
        u.x = (unsigned)f2bf(a.x) | ((unsigned)f2bf(a.y) << 16);
        u.y = (unsigned)f2bf(a.z) | ((unsigned)f2bf(a.w) << 16);
        u.z = (unsigned)f2bf(b.x) | ((unsigned)f2bf(b.y) << 16);
        u.w = (unsigned)f2bf(b.z) | ((unsigned)f2bf(b.w) << 16);
        const size_t row = t >> 5;                 // 32 threads per 256-el row
        *(uint4*)(agg + row * 768 + (t & 31) * 8) = u;
        return;
    }
    // ---- weight prep: one block per K-slab, LDS transpose ----
    const int slab = p - 2048;           // 0..23
    const int n = tid;                   // 0..255
#pragma unroll
    for (int kk = 0; kk < 32; ++kk) {
        const int k = slab * 32 + kk;    // 0..255 w_t, 256..511 w_r, 512..767 w_l
        const float* s = (k < 256) ? wt : ((k < 512) ? wrp : wl);
        T[n * 40 + kk] = f2bf(s[(k & 255) * OO + n]);
    }
    __syncthreads();
    uint4* dst = (uint4*)(wsb + slab * 8192 + n * 32);
    const uint4* src = (const uint4*)&T[n * 40];
#pragma unroll
    for (int q = 0; q < 4; ++q) dst[q] = src[q];
}

// ---------------------------------------------------------------------------
// Kernel 1: gather + reduce. One node per wave. Reads child rows from
// agg[:,0:256] (bf16, XCD-local), writes agg[:,256:768]. No parent work.
// al = (sum of present children) - ar  (identical coefficients to reference).
// ---------------------------------------------------------------------------
__global__ __launch_bounds__(256, 8) void gather(
    const int* __restrict__ children, unsigned short* __restrict__ agg) {

    const int wave = threadIdx.x >> 6;
    const int lane = threadIdx.x & 63;
    const int p = blockIdx.x;                    // 4096 blocks
    const int g = (p & 7) * 512 + (p >> 3);      // XCD x owns nodes [x*2048,+2048)
    const int nf = __builtin_amdgcn_readfirstlane(g * 4 + wave);
    const int brow = nf & ~511;                  // b*512

    const int* chp = children + (nf << 4);
    int cj[CC];
#pragma unroll
    for (int j = 0; j < CC; ++j) cj[j] = chp[j];     // scalar loads
    int ns = 0;
#pragma unroll
    for (int j = 0; j < CC; ++j) ns += (cj[j] != 0) ? 1 : 0;
    const float inv_den = (ns > 1) ? 1.0f / (float)(ns - 1) : 0.0f;
    const bool single = (ns == 1);

    // ---- issue all 16 child-row loads (8 B/lane, saddr + shared voffset) ----
    uint2 ec[CC];
#pragma unroll
    for (int j = 0; j < CC; ++j)
        ec[j] = *(const uint2*)(agg + (size_t)(brow + cj[j]) * 768 + lane * 4);

    // ---- reduce: ar = sum cr*e ; asum = sum has*e ; al = asum - ar ----
    float4 ar = make_float4(0.f, 0.f, 0.f, 0.f);
    float4 as = make_float4(0.f, 0.f, 0.f, 0.f);
#pragma unroll
    for (int j = 0; j < CC; ++j) {
        const float hasf = (cj[j] != 0) ? 1.0f : 0.0f;
        const float crr = single ? ((j == 0) ? 0.5f : 0.0f) : (float)j * inv_den;
        const float cr = crr * hasf;
        const float e0 = __builtin_bit_cast(float, ec[j].x << 16);
        const float e1 = __builtin_bit_cast(float, ec[j].x & 0xFFFF0000u);
        const float e2 = __builtin_bit_cast(float, ec[j].y << 16);
        const float e3 = __builtin_bit_cast(float, ec[j].y & 0xFFFF0000u);
        ar.x += cr * e0;   ar.y += cr * e1;   ar.z += cr * e2;   ar.w += cr * e3;
        as.x += hasf * e0; as.y += hasf * e1; as.z += hasf * e2; as.w += hasf * e3;
    }
    const float4 al = make_float4(as.x - ar.x, as.y - ar.y,
                                  as.z - ar.z, as.w - ar.w);

    // ---- store: two contiguous 512 B wave stores ----
    unsigned short* rowp = agg + (size_t)nf * 768;
    uint2 u;
    u.x = (unsigned)f2bf(ar.x) | ((unsigned)f2bf(ar.y) << 16);
    u.y = (unsigned)f2bf(ar.z) | ((unsigned)f2bf(ar.w) << 16);
    *(uint2*)(rowp + 256 + lane * 4) = u;
    u.x = (unsigned)f2bf(al.x) | ((unsigned)f2bf(al.y) << 16);
    u.y = (unsigned)f2bf(al.z) | ((unsigned)f2bf(al.w) << 16);
    *(uint2*)(rowp + 512 + lane * 4) = u;
}

// ---------------------------------------------------------------------------
// Kernel 2: GEMM (16384 x 768) x (768 x 256) + bias + leaky_relu -> out fp32
// 64x128 tile, 512 blocks (2/CU), dbuf LDS, global_load_lds staging.
// A is row-major agg: per-lane strided global addresses, same LDS layout.
// Block swizzle matches gather's XCD ownership -> A slabs hit LOCAL L2.
// ---------------------------------------------------------------------------
__global__ __launch_bounds__(256, 2) void gemm_ep(
    const unsigned short* __restrict__ agg, const unsigned short* __restrict__ wsb,
    const float* __restrict__ conv, float* __restrict__ out) {

    __shared__ unsigned short Ab[2][2048];       // 2 x 4 KB  (64 rows x 32 k)
    __shared__ unsigned short Bb[2][4096];       // 2 x 8 KB  (128 cols x 32 k)

    const int tid  = threadIdx.x;
    const int wave = tid >> 6;
    const int lane = tid & 63;
    const int quad = lane >> 4;
    const int l16  = lane & 15;
    // XCD-aligned: mtile m covers nodes m*64, gathered/converted on XCD m>>5.
    const int x = blockIdx.x & 7;
    const int q = blockIdx.x >> 3;               // 0..63
    const int mtile = x * 32 + (q >> 1);         // 0..255
    const int ntile = q & 1;
    const int wrr = wave >> 1;                   // M half (32 rows)
    const int wcc = wave & 1;                    // N half (64 cols)

    const char* aggb = (const char*)agg + (size_t)mtile * (64 * 1536);
    const char* wsbb = (const char*)wsb + ntile * 8192;
    const int toff  = tid * 16;
    const int wbase = (tid & ~63) * 16;          // wave-uniform LDS offset
    // A global address: thread t covers row t>>2 (64 rows), 16 B chunk t&3
    const char* arow = aggb + (size_t)(tid >> 2) * 1536 + (tid & 3) * 16;

    f32x4 acc[2][4];
#pragma unroll
    for (int mi = 0; mi < 2; ++mi)
#pragma unroll
        for (int ni = 0; ni < 4; ++ni)
            acc[mi][ni] = (f32x4){0.f, 0.f, 0.f, 0.f};

    auto stage = [&](int s, int b) {
        cp16(arow + s * 64, (char*)&Ab[b][0] + wbase);     // 64 B per row slab
        const char* gb = wsbb + s * 16384 + toff;          // 8 KB B chunk
        cp16(gb,        (char*)&Bb[b][0] + wbase);
        cp16(gb + 4096, (char*)&Bb[b][0] + wbase + 4096);
    };

    stage(0, 0);
#pragma unroll 1
    for (int s = 0; s < NSLAB; ++s) {
        const int cur = s & 1;
        __syncthreads();                  // staging of slab s complete
        if (s + 1 < NSLAB) stage(s + 1, cur ^ 1);

        bf16x8 af[2], bfr[4];
#pragma unroll
        for (int mi = 0; mi < 2; ++mi)
            af[mi] = *(const bf16x8*)&Ab[cur][(wrr * 32 + mi * 16 + l16) * 32 + quad * 8];
#pragma unroll
        for (int ni = 0; ni < 4; ++ni)
            bfr[ni] = *(const bf16x8*)&Bb[cur][(wcc * 64 + ni * 16 + l16) * 32 + quad * 8];
#pragma unroll
        for (int mi = 0; mi < 2; ++mi)
#pragma unroll
            for (int ni = 0; ni < 4; ++ni)
                acc[mi][ni] = __builtin_amdgcn_mfma_f32_16x16x32_bf16(
                    af[mi], bfr[ni], acc[mi][ni], 0, 0, 0);
    }

    // epilogue: + conv, leaky_relu(0.01), fp32 store
#pragma unroll
    for (int ni = 0; ni < 4; ++ni) {
        const int col = ntile * 128 + wcc * 64 + ni * 16 + l16;
        const float cv = conv[col];
#pragma unroll
        for (int mi = 0; mi < 2; ++mi) {
#pragma unroll
            for (int r = 0; r < 4; ++r) {
                const int row = mtile * 64 + wrr * 32 + mi * 16 + quad * 4 + r;
                float v = acc[mi][ni][r] + cv;
                v = (v > 0.f) ? v : 0.01f * v;
                out[(size_t)row * OO + col] = v;
            }
        }
    }
}

extern "C" void kernel_launch(void* const* d_in, const int* in_sizes, int n_in,
                              void* d_out, int out_size, void* d_ws, size_t ws_size,
                              hipStream_t stream) {
    // setup_inputs order: nodes, w_t, w_l, w_r, conv, children
    const float* nodes    = (const float*)d_in[0];
    const float* w_t      = (const float*)d_in[1];
    const float* w_l      = (const float*)d_in[2];
    const float* w_r      = (const float*)d_in[3];
    const float* conv     = (const float*)d_in[4];
    const int*   children = (const int*)d_in[5];

    unsigned short* agg = (unsigned short*)d_ws;          // 25,165,824 B
    unsigned short* wsb = agg + AGG_ELS;                  // +   393,216 B

    prep<<<2048 + 24, 256, 0, stream>>>(nodes, w_t, w_r, w_l, agg, wsb);
    gather<<<4096, 256, 0, stream>>>(children, agg);
    gemm_ep<<<512, 256, 0, stream>>>(agg, wsb, conv, (float*)d_out);
}